// Round 1
// baseline (341.313 us; speedup 1.0000x reference)
//
#include <hip/hip_runtime.h>
#include <math.h>

#define NB 8
#define LQ 2048

typedef __attribute__((ext_vector_type(4))) float f32x4;
typedef __attribute__((ext_vector_type(8))) short s16x8;

__device__ __forceinline__ unsigned f2bf_u(float f) {
  unsigned u = __builtin_bit_cast(unsigned, f);
  u += 0x7FFFu + ((u >> 16) & 1u); // RNE
  return u >> 16;
}
__device__ __forceinline__ float bf2f(unsigned h) {
  unsigned u = h << 16;
  return __builtin_bit_cast(float, u);
}

#define MFMA16 __builtin_amdgcn_mfma_f32_16x16x32_bf16

// ---------------------------------------------------------------------------
// Kernel 1: W [1024][64] fp32 -> wt [3 tensors][hi,lo][64 d][1024 k] bf16
// (unchanged from previous version — tiny)
// ---------------------------------------------------------------------------
__global__ __launch_bounds__(256) void wsplit_kernel(
    const float* __restrict__ Wq, const float* __restrict__ Wk,
    const float* __restrict__ Wv, short* __restrict__ wt) {
  int bk = blockIdx.x; // 16 blocks of 64 k-rows
  int z = blockIdx.y;  // tensor
  const float* W = (z == 0) ? Wq : (z == 1) ? Wk : Wv;
  __shared__ float tile[64][65];
  int t = threadIdx.x;
#pragma unroll
  for (int it = 0; it < 16; ++it) {
    int kk = it * 4 + (t >> 6);
    int d = t & 63;
    tile[kk][d] = W[(size_t)(bk * 64 + kk) * 64 + d];
  }
  __syncthreads();
#pragma unroll
  for (int it = 0; it < 16; ++it) {
    int d = it * 4 + (t >> 6);
    int kk = t & 63;
    float f = tile[kk][d];
    unsigned h = f2bf_u(f);
    unsigned l = f2bf_u(f - bf2f(h));
    wt[((size_t)(z * 2 + 0) * 64 + d) * 1024 + bk * 64 + kk] = (short)h;
    wt[((size_t)(z * 2 + 1) * 64 + d) * 1024 + bk * 64 + kk] = (short)l;
  }
}

// ---------------------------------------------------------------------------
// Kernel 2: projection GEMM y = x @ W, split-bf16 MFMA, NO LDS STAGING.
// Each lane loads its A-fragment (8 contiguous fp32 of one row) straight from
// global and converts in registers; B-fragments stream from L2-resident wt.
// No barriers in the K-loop. Outputs: q,k as separate hi/lo bf16 tensors
// [16384][64]; v transposed to vhT [n][64][2048] bf16 via one LDS epilogue.
// ---------------------------------------------------------------------------
__global__ __launch_bounds__(256) void proj_kernel(
    const float* __restrict__ xq, const float* __restrict__ xk,
    const float* __restrict__ xv, const short* __restrict__ wt,
    short* __restrict__ qhi, short* __restrict__ qlo,
    short* __restrict__ khi, short* __restrict__ klo,
    short* __restrict__ vhT) {
  int z = blockIdx.y;
  const float* x = (z == 0) ? xq : (z == 1) ? xk : xv;
  const short* wthi = wt + (size_t)(z * 2 + 0) * 64 * 1024;
  const short* wtlo = wt + (size_t)(z * 2 + 1) * 64 * 1024;
  int row0 = blockIdx.x * 128;
  int t = threadIdx.x;
  int wv = t >> 6, lane = t & 63;
  int c = lane & 15, quad = lane >> 4;
  f32x4 acc[2][4] = {};
  const float* xr0 = x + (size_t)(row0 + wv * 32 + c) * 1024;
  const float* xr1 = xr0 + 16 * 1024;
  for (int kb = 0; kb < 16; ++kb) {
#pragma unroll
    for (int kc = 0; kc < 2; ++kc) {
      int ko = kb * 64 + kc * 32 + quad * 8;
      s16x8 ah[2], al[2];
#pragma unroll
      for (int rs = 0; rs < 2; ++rs) {
        const float* xr = rs ? xr1 : xr0;
        f32x4 a0 = *(const f32x4*)&xr[ko];
        f32x4 a1 = *(const f32x4*)&xr[ko + 4];
#pragma unroll
        for (int j = 0; j < 4; ++j) {
          unsigned h0 = f2bf_u(a0[j]);
          ah[rs][j] = (short)h0;
          al[rs][j] = (short)f2bf_u(a0[j] - bf2f(h0));
          unsigned h1 = f2bf_u(a1[j]);
          ah[rs][4 + j] = (short)h1;
          al[rs][4 + j] = (short)f2bf_u(a1[j] - bf2f(h1));
        }
      }
#pragma unroll
      for (int cs = 0; cs < 4; ++cs) {
        s16x8 bh = *(const s16x8*)&wthi[(size_t)(cs * 16 + c) * 1024 + ko];
        s16x8 bl = *(const s16x8*)&wtlo[(size_t)(cs * 16 + c) * 1024 + ko];
#pragma unroll
        for (int rs = 0; rs < 2; ++rs) {
          acc[rs][cs] = MFMA16(ah[rs], bh, acc[rs][cs], 0, 0, 0);
          acc[rs][cs] = MFMA16(ah[rs], bl, acc[rs][cs], 0, 0, 0);
          acc[rs][cs] = MFMA16(al[rs], bh, acc[rs][cs], 0, 0, 0);
        }
      }
    }
  }
  // epilogue: C layout row=(quad*4+r), col=(lane&15)
  if (z < 2) {
    short* hi = (z == 0) ? qhi : khi;
    short* lo = (z == 0) ? qlo : klo;
#pragma unroll
    for (int rs = 0; rs < 2; ++rs)
#pragma unroll
      for (int cs = 0; cs < 4; ++cs)
#pragma unroll
        for (int r = 0; r < 4; ++r) {
          int row = row0 + wv * 32 + rs * 16 + quad * 4 + r;
          int col = cs * 16 + c;
          float val = acc[rs][cs][r];
          unsigned h = f2bf_u(val);
          unsigned l = f2bf_u(val - bf2f(h));
          hi[(size_t)row * 64 + col] = (short)h;
          lo[(size_t)row * 64 + col] = (short)l;
        }
  } else {
    // V: transpose 128x64 block -> vhT [n][64][2048] so attn's PV B-frags are
    // 16B-contiguous global reads. One LDS pass, coalesced store.
    __shared__ short vtile[64][136]; // 136*2B = 272B row stride, 16B aligned
#pragma unroll
    for (int rs = 0; rs < 2; ++rs)
#pragma unroll
      for (int cs = 0; cs < 4; ++cs)
#pragma unroll
        for (int r = 0; r < 4; ++r) {
          int rl = wv * 32 + rs * 16 + quad * 4 + r;
          vtile[cs * 16 + c][rl] = (short)f2bf_u(acc[rs][cs][r]);
        }
    __syncthreads();
    int n = row0 >> 11;        // 2048 rows per batch
    int sbase = row0 & 2047;
    int d = t >> 2, sc = (t & 3) * 32;
#pragma unroll
    for (int j = 0; j < 4; ++j) {
      s16x8 vv = *(const s16x8*)&vtile[d][sc + j * 8];
      *(s16x8*)&vhT[((size_t)n * 64 + d) * LQ + sbase + sc + j * 8] = vv;
    }
  }
}

// ---------------------------------------------------------------------------
// Kernel 3: causal flash attention, BARRIER-FREE. 1024 one-wave blocks, each
// owns 16 q-rows. K/V fragments are read directly from L2-resident global
// (no LDS staging, no __syncthreads). XCD-pinned: n = bid&7 so each XCD's L2
// holds exactly one batch's K/V (~768 KB). Split-bf16 QK^T (hh+hl+lh),
// online softmax in registers, P via per-wave LDS round-trip, bf16 PV.
// ---------------------------------------------------------------------------
__global__ __launch_bounds__(64) void attn_kernel(
    const short* __restrict__ qhi, const short* __restrict__ qlo,
    const short* __restrict__ khi, const short* __restrict__ klo,
    const short* __restrict__ vhT, float* __restrict__ outp) {
  int bid = blockIdx.x;
  int n = bid & 7;   // HW round-robins wgid across 8 XCDs -> batch per XCD
  int qt = bid >> 3; // 16-row q-tile index, 0..127
  int lane = threadIdx.x;
  int c = lane & 15, quad = lane >> 4;
  int qr0 = qt * 16;
  __shared__ short pS[16][72]; // per-wave P transpose buffer (no barrier)
  // Q A-fragments: A[m=lane&15][k=quad*8+j], hi/lo
  s16x8 qfh[2], qfl[2];
  size_t qbase = ((size_t)n * LQ + qr0 + c) * 64;
#pragma unroll
  for (int kc = 0; kc < 2; ++kc) {
    qfh[kc] = *(const s16x8*)&qhi[qbase + kc * 32 + quad * 8];
    qfl[kc] = *(const s16x8*)&qlo[qbase + kc * 32 + quad * 8];
  }
  f32x4 o[4] = {};
  float m_r[4], l_r[4];
#pragma unroll
  for (int r = 0; r < 4; ++r) { m_r[r] = -INFINITY; l_r[r] = 0.0f; }
  int ktmax = qt >> 2; // last (diagonal) 64-wide k-tile
  for (int kt = 0; kt <= ktmax; ++kt) {
    int s0 = kt * 64;
    size_t kbase = ((size_t)n * LQ + s0) * 64;
    // S = Q K^T (split-bf16: hh + hl + lh); B-frags direct from global
    f32x4 sa[4] = {};
#pragma unroll
    for (int ct = 0; ct < 4; ++ct) {
      size_t rb = kbase + (size_t)(ct * 16 + c) * 64;
#pragma unroll
      for (int kc = 0; kc < 2; ++kc) {
        s16x8 bh = *(const s16x8*)&khi[rb + kc * 32 + quad * 8];
        s16x8 bl = *(const s16x8*)&klo[rb + kc * 32 + quad * 8];
        sa[ct] = MFMA16(qfh[kc], bh, sa[ct], 0, 0, 0);
        sa[ct] = MFMA16(qfh[kc], bl, sa[ct], 0, 0, 0);
        sa[ct] = MFMA16(qfl[kc], bh, sa[ct], 0, 0, 0);
      }
    }
    // prefetch V B-fragments now (independent of softmax; hides L2 latency)
    s16x8 vb[4][2];
#pragma unroll
    for (int dt = 0; dt < 4; ++dt)
#pragma unroll
      for (int kc2 = 0; kc2 < 2; ++kc2)
        vb[dt][kc2] = *(const s16x8*)&vhT[((size_t)n * 64 + dt * 16 + c) * LQ +
                                          s0 + kc2 * 32 + quad * 8];
    // scale (faithful bug: *sqrt(D)=8) + causal mask on diagonal tile
    float sv[4][4];
    bool diag = (kt == ktmax);
#pragma unroll
    for (int ct = 0; ct < 4; ++ct)
#pragma unroll
      for (int r = 0; r < 4; ++r) {
        float xsc = sa[ct][r] * 8.0f;
        if (diag) {
          int sg = s0 + ct * 16 + c;
          int qg = qr0 + quad * 4 + r;
          if (sg > qg) xsc = -INFINITY;
        }
        sv[ct][r] = xsc;
      }
    // online softmax, rows = quad*4+r, reduce across the 16 lanes of the quad
    float alpha[4];
#pragma unroll
    for (int r = 0; r < 4; ++r) {
      float mx = fmaxf(fmaxf(sv[0][r], sv[1][r]), fmaxf(sv[2][r], sv[3][r]));
#pragma unroll
      for (int off = 1; off < 16; off <<= 1) mx = fmaxf(mx, __shfl_xor(mx, off, 64));
      float mnew = fmaxf(m_r[r], mx);
      alpha[r] = exp2f((m_r[r] - mnew) * 1.44269504088896f);
      m_r[r] = mnew;
      float rs = 0.0f;
#pragma unroll
      for (int ct = 0; ct < 4; ++ct) {
        float p = exp2f((sv[ct][r] - mnew) * 1.44269504088896f);
        sv[ct][r] = p;
        rs += p;
      }
#pragma unroll
      for (int off = 1; off < 16; off <<= 1) rs += __shfl_xor(rs, off, 64);
      l_r[r] = l_r[r] * alpha[r] + rs;
    }
#pragma unroll
    for (int dt = 0; dt < 4; ++dt)
#pragma unroll
      for (int r = 0; r < 4; ++r) o[dt][r] *= alpha[r];
    // P: C-layout -> per-wave LDS -> A-layout (single wave, no barrier needed)
#pragma unroll
    for (int ct = 0; ct < 4; ++ct)
#pragma unroll
      for (int r = 0; r < 4; ++r)
        pS[quad * 4 + r][ct * 16 + c] = (short)f2bf_u(sv[ct][r]);
    s16x8 pa[2];
#pragma unroll
    for (int kc2 = 0; kc2 < 2; ++kc2)
      pa[kc2] = *(const s16x8*)&pS[c][kc2 * 32 + quad * 8];
    // O += P V
#pragma unroll
    for (int dt = 0; dt < 4; ++dt)
#pragma unroll
      for (int kc2 = 0; kc2 < 2; ++kc2)
        o[dt] = MFMA16(pa[kc2], vb[dt][kc2], o[dt], 0, 0, 0);
  }
  // epilogue: normalize and store fp32
#pragma unroll
  for (int dt = 0; dt < 4; ++dt)
#pragma unroll
    for (int r = 0; r < 4; ++r)
      outp[((size_t)n * LQ + qr0 + quad * 4 + r) * 64 + dt * 16 + c] =
          o[dt][r] / l_r[r];
}

// ---------------------------------------------------------------------------
extern "C" void kernel_launch(void* const* d_in, const int* in_sizes, int n_in,
                              void* d_out, int out_size, void* d_ws, size_t ws_size,
                              hipStream_t stream) {
  const float* q = (const float*)d_in[0];
  const float* k = (const float*)d_in[1];
  const float* v = (const float*)d_in[2];
  const float* Wq = (const float*)d_in[3];
  const float* Wk = (const float*)d_in[4];
  const float* Wv = (const float*)d_in[5];
  // d_in[6] = attn_mask: ignored (known causal triu mask)
  float* out = (float*)d_out;

  char* ws = (char*)d_ws;
  // ws layout (same 11,272,192 B total as previous version):
  //   wt   3*2*64*1024 shorts = 786432 B
  //   qhi/qlo/khi/klo  each 16384*64 shorts = 2097152 B
  //   vhT  8*64*2048 shorts = 2097152 B
  short* wt  = (short*)ws;
  short* qhi = (short*)(ws + 786432);
  short* qlo = qhi + (size_t)16384 * 64;
  short* khi = qlo + (size_t)16384 * 64;
  short* klo = khi + (size_t)16384 * 64;
  short* vhT = klo + (size_t)16384 * 64;

  wsplit_kernel<<<dim3(16, 3), 256, 0, stream>>>(Wq, Wk, Wv, wt);
  proj_kernel<<<dim3(128, 3), 256, 0, stream>>>(q, k, v, wt, qhi, qlo, khi, klo, vhT);
  attn_kernel<<<dim3(1024), 64, 0, stream>>>(qhi, qlo, khi, klo, vhT, out);
}

// Round 2
// 327.121 us; speedup vs baseline: 1.0434x; 1.0434x over previous
//
#include <hip/hip_runtime.h>
#include <math.h>

#define NB 8
#define LQ 2048
#define LOG2E 1.44269504088896f

typedef __attribute__((ext_vector_type(4))) float f32x4;
typedef __attribute__((ext_vector_type(8))) short s16x8;

__device__ __forceinline__ unsigned f2bf_u(float f) {
  unsigned u = __builtin_bit_cast(unsigned, f);
  u += 0x7FFFu + ((u >> 16) & 1u); // RNE
  return u >> 16;
}
__device__ __forceinline__ float bf2f(unsigned h) {
  unsigned u = h << 16;
  return __builtin_bit_cast(float, u);
}

#define MFMA16 __builtin_amdgcn_mfma_f32_16x16x32_bf16

// ---------------------------------------------------------------------------
// Kernel 1: W [1024][64] fp32 -> wt [3 tensors][hi,lo][64 d][1024 k] bf16
// ---------------------------------------------------------------------------
__global__ __launch_bounds__(256) void wsplit_kernel(
    const float* __restrict__ Wq, const float* __restrict__ Wk,
    const float* __restrict__ Wv, short* __restrict__ wt) {
  int bk = blockIdx.x; // 16 blocks of 64 k-rows
  int z = blockIdx.y;  // tensor
  const float* W = (z == 0) ? Wq : (z == 1) ? Wk : Wv;
  __shared__ float tile[64][65];
  int t = threadIdx.x;
#pragma unroll
  for (int it = 0; it < 16; ++it) {
    int kk = it * 4 + (t >> 6);
    int d = t & 63;
    tile[kk][d] = W[(size_t)(bk * 64 + kk) * 64 + d];
  }
  __syncthreads();
#pragma unroll
  for (int it = 0; it < 16; ++it) {
    int d = it * 4 + (t >> 6);
    int kk = t & 63;
    float f = tile[kk][d];
    unsigned h = f2bf_u(f);
    unsigned l = f2bf_u(f - bf2f(h));
    wt[((size_t)(z * 2 + 0) * 64 + d) * 1024 + bk * 64 + kk] = (short)h;
    wt[((size_t)(z * 2 + 1) * 64 + d) * 1024 + bk * 64 + kk] = (short)l;
  }
}

// ---------------------------------------------------------------------------
// Kernel 2: projection GEMM y = x @ W, split-bf16 MFMA, direct-from-global
// with explicit register double-buffering. BM=64, 4 waves x 16 rows, grid
// (256,3) = 768 blocks = 3 blocks/CU, launch_bounds caps VGPR for 3 wv/SIMD.
// A(kb+1) loads issued while MFMA(kb) runs; B loads covered by convert VALU.
// ---------------------------------------------------------------------------
__global__ __launch_bounds__(256, 3) void proj_kernel(
    const float* __restrict__ xq, const float* __restrict__ xk,
    const float* __restrict__ xv, const short* __restrict__ wt,
    short* __restrict__ qhi, short* __restrict__ qlo,
    short* __restrict__ khi, short* __restrict__ klo,
    short* __restrict__ vhT) {
  int z = blockIdx.y;
  const float* x = (z == 0) ? xq : (z == 1) ? xk : xv;
  const short* wthi = wt + (size_t)(z * 2 + 0) * 64 * 1024;
  const short* wtlo = wt + (size_t)(z * 2 + 1) * 64 * 1024;
  int row0 = blockIdx.x * 64;
  int t = threadIdx.x;
  int wv = t >> 6, lane = t & 63;
  int c = lane & 15, quad = lane >> 4;
  const float* xp = x + (size_t)(row0 + wv * 16 + c) * 1024 + quad * 8;
  f32x4 acc[4] = {};
  // prologue: A regs for kb=0 (kc0: p0,p1 ; kc1: p2,p3)
  f32x4 p0 = *(const f32x4*)(xp + 0);
  f32x4 p1 = *(const f32x4*)(xp + 4);
  f32x4 p2 = *(const f32x4*)(xp + 32);
  f32x4 p3 = *(const f32x4*)(xp + 36);
  for (int kb = 0; kb < 16; ++kb) {
    // B loads for this kb (L2-resident; covered by the convert VALU below)
    s16x8 bh0[4], bl0[4], bh1[4], bl1[4];
    int ko = kb * 64 + quad * 8;
#pragma unroll
    for (int cs = 0; cs < 4; ++cs) {
      const short* bp = wthi + (size_t)(cs * 16 + c) * 1024 + ko;
      const short* lp = wtlo + (size_t)(cs * 16 + c) * 1024 + ko;
      bh0[cs] = *(const s16x8*)(bp);
      bh1[cs] = *(const s16x8*)(bp + 32);
      bl0[cs] = *(const s16x8*)(lp);
      bl1[cs] = *(const s16x8*)(lp + 32);
    }
    // convert current A fp32 -> hi/lo bf16 fragments
    s16x8 ah0, al0, ah1, al1;
#pragma unroll
    for (int j = 0; j < 4; ++j) {
      unsigned h;
      h = f2bf_u(p0[j]); ah0[j] = (short)h;     al0[j] = (short)f2bf_u(p0[j] - bf2f(h));
      h = f2bf_u(p1[j]); ah0[4 + j] = (short)h; al0[4 + j] = (short)f2bf_u(p1[j] - bf2f(h));
      h = f2bf_u(p2[j]); ah1[j] = (short)h;     al1[j] = (short)f2bf_u(p2[j] - bf2f(h));
      h = f2bf_u(p3[j]); ah1[4 + j] = (short)h; al1[4 + j] = (short)f2bf_u(p3[j] - bf2f(h));
    }
    // prefetch A for kb+1 (hidden under the 24 MFMAs below)
    if (kb < 15) {
      xp += 64;
      p0 = *(const f32x4*)(xp + 0);
      p1 = *(const f32x4*)(xp + 4);
      p2 = *(const f32x4*)(xp + 32);
      p3 = *(const f32x4*)(xp + 36);
    }
    // MFMA: split-bf16 (hh + hl + lh)
#pragma unroll
    for (int cs = 0; cs < 4; ++cs) {
      acc[cs] = MFMA16(ah0, bh0[cs], acc[cs], 0, 0, 0);
      acc[cs] = MFMA16(ah0, bl0[cs], acc[cs], 0, 0, 0);
      acc[cs] = MFMA16(al0, bh0[cs], acc[cs], 0, 0, 0);
    }
#pragma unroll
    for (int cs = 0; cs < 4; ++cs) {
      acc[cs] = MFMA16(ah1, bh1[cs], acc[cs], 0, 0, 0);
      acc[cs] = MFMA16(ah1, bl1[cs], acc[cs], 0, 0, 0);
      acc[cs] = MFMA16(al1, bh1[cs], acc[cs], 0, 0, 0);
    }
  }
  // epilogue: C layout row=(quad*4+r), col=(lane&15)
  if (z < 2) {
    short* hi = (z == 0) ? qhi : khi;
    short* lo = (z == 0) ? qlo : klo;
#pragma unroll
    for (int cs = 0; cs < 4; ++cs)
#pragma unroll
      for (int r = 0; r < 4; ++r) {
        int row = row0 + wv * 16 + quad * 4 + r;
        int col = cs * 16 + c;
        float val = acc[cs][r];
        unsigned h = f2bf_u(val);
        unsigned l = f2bf_u(val - bf2f(h));
        hi[(size_t)row * 64 + col] = (short)h;
        lo[(size_t)row * 64 + col] = (short)l;
      }
  } else {
    // V: transpose 64x64 block -> vhT [n][64][2048]
    __shared__ short vtile[64][72];
#pragma unroll
    for (int cs = 0; cs < 4; ++cs)
#pragma unroll
      for (int r = 0; r < 4; ++r)
        vtile[cs * 16 + c][wv * 16 + quad * 4 + r] = (short)f2bf_u(acc[cs][r]);
    __syncthreads();
    int n = row0 >> 11;
    int sbase = row0 & 2047;
    int d = t >> 2, sc = (t & 3) * 16;
#pragma unroll
    for (int j = 0; j < 2; ++j) {
      s16x8 vv = *(const s16x8*)&vtile[d][sc + j * 8];
      *(s16x8*)&vhT[((size_t)n * 64 + d) * LQ + sbase + sc + j * 8] = vv;
    }
  }
}

// ---------------------------------------------------------------------------
// Kernel 3: causal flash attention, 4-way k-split. Block = one 16-row q-tile
// (256 thr / 4 waves); wave wv handles kt = wv, wv+4, ... (round-robin
// balances the causal triangle). Partial (m,l,o) merged via LDS at the end.
// K/V fragments read directly from L2-resident global; heaviest q-tiles are
// launched first. XCD-pinned: n = bid&7.
// ---------------------------------------------------------------------------
__global__ __launch_bounds__(256, 3) void attn_kernel(
    const short* __restrict__ qhi, const short* __restrict__ qlo,
    const short* __restrict__ khi, const short* __restrict__ klo,
    const short* __restrict__ vhT, float* __restrict__ outp) {
  int bid = blockIdx.x;
  int n = bid & 7;
  int qt = 127 - (bid >> 3); // heavy (high-qt) tiles first
  int t = threadIdx.x;
  int wv = t >> 6, lane = t & 63;
  int c = lane & 15, quad = lane >> 4;
  int qr0 = qt * 16;
  __shared__ short pS[4][16][72]; // per-wave P transpose buffer
  __shared__ float mS[4][16], lS[4][16];
  __shared__ float oS[4][16][64];
  // Q A-fragments: A[m=lane&15][k=quad*8+j], hi/lo
  s16x8 qfh[2], qfl[2];
  size_t qbase = ((size_t)n * LQ + qr0 + c) * 64;
#pragma unroll
  for (int kc = 0; kc < 2; ++kc) {
    qfh[kc] = *(const s16x8*)&qhi[qbase + kc * 32 + quad * 8];
    qfl[kc] = *(const s16x8*)&qlo[qbase + kc * 32 + quad * 8];
  }
  f32x4 o[4] = {};
  float m_r[4], l_r[4];
#pragma unroll
  for (int r = 0; r < 4; ++r) { m_r[r] = -INFINITY; l_r[r] = 0.0f; }
  int ktmax = qt >> 2; // last (diagonal) 64-wide k-tile
  for (int kt = wv; kt <= ktmax; kt += 4) {
    int s0 = kt * 64;
    size_t kbase = ((size_t)n * LQ + s0) * 64;
    // S = Q K^T (split-bf16: hh + hl + lh); B-frags direct from global
    f32x4 sa[4] = {};
#pragma unroll
    for (int ct = 0; ct < 4; ++ct) {
      size_t rb = kbase + (size_t)(ct * 16 + c) * 64;
#pragma unroll
      for (int kc = 0; kc < 2; ++kc) {
        s16x8 bh = *(const s16x8*)&khi[rb + kc * 32 + quad * 8];
        s16x8 bl = *(const s16x8*)&klo[rb + kc * 32 + quad * 8];
        sa[ct] = MFMA16(qfh[kc], bh, sa[ct], 0, 0, 0);
        sa[ct] = MFMA16(qfh[kc], bl, sa[ct], 0, 0, 0);
        sa[ct] = MFMA16(qfl[kc], bh, sa[ct], 0, 0, 0);
      }
    }
    // prefetch V B-fragments (independent of softmax; hides L2 latency)
    s16x8 vb[4][2];
#pragma unroll
    for (int dt = 0; dt < 4; ++dt)
#pragma unroll
      for (int kc2 = 0; kc2 < 2; ++kc2)
        vb[dt][kc2] = *(const s16x8*)&vhT[((size_t)n * 64 + dt * 16 + c) * LQ +
                                          s0 + kc2 * 32 + quad * 8];
    // scale (faithful bug: *sqrt(D)=8) + causal mask on diagonal tile
    float sv[4][4];
    bool diag = (kt == ktmax);
#pragma unroll
    for (int ct = 0; ct < 4; ++ct)
#pragma unroll
      for (int r = 0; r < 4; ++r) {
        float xsc = sa[ct][r] * 8.0f;
        if (diag) {
          int sg = s0 + ct * 16 + c;
          int qg = qr0 + quad * 4 + r;
          if (sg > qg) xsc = -INFINITY;
        }
        sv[ct][r] = xsc;
      }
    // online softmax, rows = quad*4+r, reduce across the 16 lanes of the quad
    float alpha[4];
#pragma unroll
    for (int r = 0; r < 4; ++r) {
      float mx = fmaxf(fmaxf(sv[0][r], sv[1][r]), fmaxf(sv[2][r], sv[3][r]));
#pragma unroll
      for (int off = 1; off < 16; off <<= 1) mx = fmaxf(mx, __shfl_xor(mx, off, 64));
      float mnew = fmaxf(m_r[r], mx);
      alpha[r] = exp2f((m_r[r] - mnew) * LOG2E);
      m_r[r] = mnew;
      float rs = 0.0f;
#pragma unroll
      for (int ct = 0; ct < 4; ++ct) {
        float p = exp2f((sv[ct][r] - mnew) * LOG2E);
        sv[ct][r] = p;
        rs += p;
      }
#pragma unroll
      for (int off = 1; off < 16; off <<= 1) rs += __shfl_xor(rs, off, 64);
      l_r[r] = l_r[r] * alpha[r] + rs;
    }
#pragma unroll
    for (int dt = 0; dt < 4; ++dt)
#pragma unroll
      for (int r = 0; r < 4; ++r) o[dt][r] *= alpha[r];
    // P: C-layout -> per-wave LDS -> A-layout (single wave region, no barrier)
#pragma unroll
    for (int ct = 0; ct < 4; ++ct)
#pragma unroll
      for (int r = 0; r < 4; ++r)
        pS[wv][quad * 4 + r][ct * 16 + c] = (short)f2bf_u(sv[ct][r]);
    s16x8 pa[2];
#pragma unroll
    for (int kc2 = 0; kc2 < 2; ++kc2)
      pa[kc2] = *(const s16x8*)&pS[wv][c][kc2 * 32 + quad * 8];
    // O += P V
#pragma unroll
    for (int dt = 0; dt < 4; ++dt)
#pragma unroll
      for (int kc2 = 0; kc2 < 2; ++kc2)
        o[dt] = MFMA16(pa[kc2], vb[dt][kc2], o[dt], 0, 0, 0);
  }
  // write per-wave partials to LDS
#pragma unroll
  for (int dt = 0; dt < 4; ++dt)
#pragma unroll
    for (int r = 0; r < 4; ++r)
      oS[wv][quad * 4 + r][dt * 16 + c] = o[dt][r];
  if (c == 0) {
#pragma unroll
    for (int r = 0; r < 4; ++r) {
      mS[wv][quad * 4 + r] = m_r[r];
      lS[wv][quad * 4 + r] = l_r[r];
    }
  }
  __syncthreads();
  // merge 4 partials: thread t owns (row = t>>4, cols (t&15)*4 .. +3)
  {
    int r = t >> 4;
    int c4 = (t & 15) * 4;
    float m0 = mS[0][r], m1 = mS[1][r], m2 = mS[2][r], m3 = mS[3][r];
    float mstar = fmaxf(fmaxf(m0, m1), fmaxf(m2, m3));
    float s0 = exp2f((m0 - mstar) * LOG2E);
    float s1 = exp2f((m1 - mstar) * LOG2E);
    float s2 = exp2f((m2 - mstar) * LOG2E);
    float s3 = exp2f((m3 - mstar) * LOG2E);
    float lstar = s0 * lS[0][r] + s1 * lS[1][r] + s2 * lS[2][r] + s3 * lS[3][r];
    float inv = 1.0f / lstar;
    f32x4 oa;
#pragma unroll
    for (int j = 0; j < 4; ++j)
      oa[j] = (s0 * oS[0][r][c4 + j] + s1 * oS[1][r][c4 + j] +
               s2 * oS[2][r][c4 + j] + s3 * oS[3][r][c4 + j]) * inv;
    *(f32x4*)&outp[((size_t)n * LQ + qr0 + r) * 64 + c4] = oa;
  }
}

// ---------------------------------------------------------------------------
extern "C" void kernel_launch(void* const* d_in, const int* in_sizes, int n_in,
                              void* d_out, int out_size, void* d_ws, size_t ws_size,
                              hipStream_t stream) {
  const float* q = (const float*)d_in[0];
  const float* k = (const float*)d_in[1];
  const float* v = (const float*)d_in[2];
  const float* Wq = (const float*)d_in[3];
  const float* Wk = (const float*)d_in[4];
  const float* Wv = (const float*)d_in[5];
  // d_in[6] = attn_mask: ignored (known causal triu mask)
  float* out = (float*)d_out;

  char* ws = (char*)d_ws;
  // ws layout:
  //   wt   3*2*64*1024 shorts = 786432 B
  //   qhi/qlo/khi/klo  each 16384*64 shorts = 2097152 B
  //   vhT  8*64*2048 shorts = 2097152 B
  short* wt  = (short*)ws;
  short* qhi = (short*)(ws + 786432);
  short* qlo = qhi + (size_t)16384 * 64;
  short* khi = qlo + (size_t)16384 * 64;
  short* klo = khi + (size_t)16384 * 64;
  short* vhT = klo + (size_t)16384 * 64;

  wsplit_kernel<<<dim3(16, 3), 256, 0, stream>>>(Wq, Wk, Wv, wt);
  proj_kernel<<<dim3(256, 3), 256, 0, stream>>>(q, k, v, wt, qhi, qlo, khi, klo, vhT);
  attn_kernel<<<dim3(1024), 256, 0, stream>>>(qhi, qlo, khi, klo, vhT, out);
}

// Round 3
// 310.261 us; speedup vs baseline: 1.1001x; 1.0543x over previous
//
#include <hip/hip_runtime.h>
#include <math.h>

#define NB 8
#define LQ 2048
#define LOG2E 1.44269504088896f

typedef __attribute__((ext_vector_type(4))) float f32x4;
typedef __attribute__((ext_vector_type(8))) short s16x8;

__device__ __forceinline__ unsigned f2bf_u(float f) {
  unsigned u = __builtin_bit_cast(unsigned, f);
  u += 0x7FFFu + ((u >> 16) & 1u); // RNE
  return u >> 16;
}
__device__ __forceinline__ float bf2f(unsigned h) {
  unsigned u = h << 16;
  return __builtin_bit_cast(float, u);
}

#define MFMA16 __builtin_amdgcn_mfma_f32_16x16x32_bf16

// ---------------------------------------------------------------------------
// Kernel 1: W [1024][64] fp32 -> wt [3 tensors][hi,lo][64 d][1024 k] bf16
// ---------------------------------------------------------------------------
__global__ __launch_bounds__(256) void wsplit_kernel(
    const float* __restrict__ Wq, const float* __restrict__ Wk,
    const float* __restrict__ Wv, short* __restrict__ wt) {
  int bk = blockIdx.x; // 16 blocks of 64 k-rows
  int z = blockIdx.y;  // tensor
  const float* W = (z == 0) ? Wq : (z == 1) ? Wk : Wv;
  __shared__ float tile[64][65];
  int t = threadIdx.x;
#pragma unroll
  for (int it = 0; it < 16; ++it) {
    int kk = it * 4 + (t >> 6);
    int d = t & 63;
    tile[kk][d] = W[(size_t)(bk * 64 + kk) * 64 + d];
  }
  __syncthreads();
#pragma unroll
  for (int it = 0; it < 16; ++it) {
    int d = it * 4 + (t >> 6);
    int kk = t & 63;
    float f = tile[kk][d];
    unsigned h = f2bf_u(f);
    unsigned l = f2bf_u(f - bf2f(h));
    wt[((size_t)(z * 2 + 0) * 64 + d) * 1024 + bk * 64 + kk] = (short)h;
    wt[((size_t)(z * 2 + 1) * 64 + d) * 1024 + bk * 64 + kk] = (short)l;
  }
}

// ---------------------------------------------------------------------------
// Kernel 2: projection GEMM y = x @ W via split-bf16 MFMA.
// m97-style: A fp32 tile staged with global_load_lds (async, compiler cannot
// sink it), double-buffered LDS, one barrier per K-step. LDS dest is linear
// (gload_lds requirement); bank conflicts on the A-fragment read are killed
// by a 16B-granularity XOR swizzle applied to the per-lane GLOBAL source and
// to the ds_read address (same involution both sides).
// B fragments (pre-split bf16 wt, L2-resident) load straight to registers.
// BM=64, BK=64, 4 waves x 16 rows, grid (256,3) = 3 blocks/CU.
// ---------------------------------------------------------------------------
__global__ __launch_bounds__(256, 3) void proj_kernel(
    const float* __restrict__ xq, const float* __restrict__ xk,
    const float* __restrict__ xv, const short* __restrict__ wt,
    short* __restrict__ qhi, short* __restrict__ qlo,
    short* __restrict__ khi, short* __restrict__ klo,
    short* __restrict__ vhT) {
  int z = blockIdx.y;
  const float* x = (z == 0) ? xq : (z == 1) ? xk : xv;
  const short* wthi = wt + (size_t)(z * 2 + 0) * 64 * 1024;
  const short* wtlo = wt + (size_t)(z * 2 + 1) * 64 * 1024;
  int row0 = blockIdx.x * 64;
  int t = threadIdx.x;
  int wv = t >> 6, lane = t & 63;
  int c = lane & 15, quad = lane >> 4;

  __shared__ float xa[2][64 * 64]; // 2 x 16KB, linear [row][64] fp32 per buf
  __shared__ short vtile[64][72];  // z==2 epilogue transpose

  const float* xg = x + (size_t)row0 * 1024; // + row*1024 + kb*64 + swz

  // stage tile kb into buf: 4 gload_lds_dwordx4 per wave, linear LDS dest,
  // global source pre-swizzled: 16B-chunk c reads chunk (c ^ (row&7)).
#define STAGE(buf, kb)                                                        \
  {                                                                           \
    _Pragma("unroll") for (int j = 0; j < 4; ++j) {                           \
      int row = wv * 16 + j * 4 + quad;                                       \
      const float* src = xg + (size_t)row * 1024 + (kb) * 64 +                \
                         ((c ^ (row & 7)) << 2);                              \
      float* dst = &xa[buf][(wv * 4 + j) * 256]; /* wave-uniform base */      \
      __builtin_amdgcn_global_load_lds(                                       \
          (const __attribute__((address_space(1))) unsigned*)src,             \
          (__attribute__((address_space(3))) unsigned*)dst, 16, 0, 0);        \
    }                                                                         \
  }

  f32x4 acc[4] = {};
  STAGE(0, 0);
  __syncthreads(); // drains vmcnt -> buf0 ready
  int cur = 0;
  int rowl = wv * 16 + c; // A-fragment row within tile
  for (int kb = 0; kb < 16; ++kb) {
    if (kb < 15) STAGE(cur ^ 1, kb + 1); // async; drains at this iter's barrier
    // B fragments for this kb (L2-resident)
    s16x8 bh[4][2], bl[4][2];
    int ko = kb * 64 + quad * 8;
#pragma unroll
    for (int cs = 0; cs < 4; ++cs) {
      const short* bp = wthi + (size_t)(cs * 16 + c) * 1024 + ko;
      const short* lp = wtlo + (size_t)(cs * 16 + c) * 1024 + ko;
      bh[cs][0] = *(const s16x8*)(bp);
      bh[cs][1] = *(const s16x8*)(bp + 32);
      bl[cs][0] = *(const s16x8*)(lp);
      bl[cs][1] = *(const s16x8*)(lp + 32);
    }
    // A fragments from LDS (swizzled read) + split-bf16 convert, then MFMA
    const float* arow = &xa[cur][rowl * 64];
#pragma unroll
    for (int kc = 0; kc < 2; ++kc) {
      int ch0 = ((kc * 8 + quad * 2 + 0) ^ (c & 7)) << 2;
      int ch1 = ((kc * 8 + quad * 2 + 1) ^ (c & 7)) << 2;
      f32x4 a0 = *(const f32x4*)(arow + ch0);
      f32x4 a1 = *(const f32x4*)(arow + ch1);
      s16x8 ah, al;
#pragma unroll
      for (int j = 0; j < 4; ++j) {
        unsigned h;
        h = f2bf_u(a0[j]); ah[j] = (short)h;     al[j] = (short)f2bf_u(a0[j] - bf2f(h));
        h = f2bf_u(a1[j]); ah[4 + j] = (short)h; al[4 + j] = (short)f2bf_u(a1[j] - bf2f(h));
      }
#pragma unroll
      for (int cs = 0; cs < 4; ++cs) {
        acc[cs] = MFMA16(ah, bh[cs][kc], acc[cs], 0, 0, 0);
        acc[cs] = MFMA16(ah, bl[cs][kc], acc[cs], 0, 0, 0);
        acc[cs] = MFMA16(al, bh[cs][kc], acc[cs], 0, 0, 0);
      }
    }
    __syncthreads(); // drains staging vmcnt; buf(cur^1) ready for next iter
    cur ^= 1;
  }
#undef STAGE
  // epilogue: C layout row=(quad*4+r), col=(lane&15)
  if (z < 2) {
    short* hi = (z == 0) ? qhi : khi;
    short* lo = (z == 0) ? qlo : klo;
#pragma unroll
    for (int cs = 0; cs < 4; ++cs)
#pragma unroll
      for (int r = 0; r < 4; ++r) {
        int row = row0 + wv * 16 + quad * 4 + r;
        int col = cs * 16 + c;
        float val = acc[cs][r];
        unsigned h = f2bf_u(val);
        unsigned l = f2bf_u(val - bf2f(h));
        hi[(size_t)row * 64 + col] = (short)h;
        lo[(size_t)row * 64 + col] = (short)l;
      }
  } else {
    // V: transpose 64x64 block -> vhT [n][64][2048]
#pragma unroll
    for (int cs = 0; cs < 4; ++cs)
#pragma unroll
      for (int r = 0; r < 4; ++r)
        vtile[cs * 16 + c][wv * 16 + quad * 4 + r] = (short)f2bf_u(acc[cs][r]);
    __syncthreads();
    int n = row0 >> 11;
    int sbase = row0 & 2047;
    int d = t >> 2, sc = (t & 3) * 16;
#pragma unroll
    for (int j = 0; j < 2; ++j) {
      s16x8 vv = *(const s16x8*)&vtile[d][sc + j * 8];
      *(s16x8*)&vhT[((size_t)n * 64 + d) * LQ + sbase + sc + j * 8] = vv;
    }
  }
}

// ---------------------------------------------------------------------------
// Kernel 3: causal flash attention, 4-way k-split. UNCHANGED from round 2
// (frozen deliberately so this round's total delta isolates the proj change).
// ---------------------------------------------------------------------------
__global__ __launch_bounds__(256, 3) void attn_kernel(
    const short* __restrict__ qhi, const short* __restrict__ qlo,
    const short* __restrict__ khi, const short* __restrict__ klo,
    const short* __restrict__ vhT, float* __restrict__ outp) {
  int bid = blockIdx.x;
  int n = bid & 7;
  int qt = 127 - (bid >> 3); // heavy (high-qt) tiles first
  int t = threadIdx.x;
  int wv = t >> 6, lane = t & 63;
  int c = lane & 15, quad = lane >> 4;
  int qr0 = qt * 16;
  __shared__ short pS[4][16][72]; // per-wave P transpose buffer
  __shared__ float mS[4][16], lS[4][16];
  __shared__ float oS[4][16][64];
  // Q A-fragments: A[m=lane&15][k=quad*8+j], hi/lo
  s16x8 qfh[2], qfl[2];
  size_t qbase = ((size_t)n * LQ + qr0 + c) * 64;
#pragma unroll
  for (int kc = 0; kc < 2; ++kc) {
    qfh[kc] = *(const s16x8*)&qhi[qbase + kc * 32 + quad * 8];
    qfl[kc] = *(const s16x8*)&qlo[qbase + kc * 32 + quad * 8];
  }
  f32x4 o[4] = {};
  float m_r[4], l_r[4];
#pragma unroll
  for (int r = 0; r < 4; ++r) { m_r[r] = -INFINITY; l_r[r] = 0.0f; }
  int ktmax = qt >> 2; // last (diagonal) 64-wide k-tile
  for (int kt = wv; kt <= ktmax; kt += 4) {
    int s0 = kt * 64;
    size_t kbase = ((size_t)n * LQ + s0) * 64;
    // S = Q K^T (split-bf16: hh + hl + lh); B-frags direct from global
    f32x4 sa[4] = {};
#pragma unroll
    for (int ct = 0; ct < 4; ++ct) {
      size_t rb = kbase + (size_t)(ct * 16 + c) * 64;
#pragma unroll
      for (int kc = 0; kc < 2; ++kc) {
        s16x8 bh = *(const s16x8*)&khi[rb + kc * 32 + quad * 8];
        s16x8 bl = *(const s16x8*)&klo[rb + kc * 32 + quad * 8];
        sa[ct] = MFMA16(qfh[kc], bh, sa[ct], 0, 0, 0);
        sa[ct] = MFMA16(qfh[kc], bl, sa[ct], 0, 0, 0);
        sa[ct] = MFMA16(qfl[kc], bh, sa[ct], 0, 0, 0);
      }
    }
    // prefetch V B-fragments (independent of softmax; hides L2 latency)
    s16x8 vb[4][2];
#pragma unroll
    for (int dt = 0; dt < 4; ++dt)
#pragma unroll
      for (int kc2 = 0; kc2 < 2; ++kc2)
        vb[dt][kc2] = *(const s16x8*)&vhT[((size_t)n * 64 + dt * 16 + c) * LQ +
                                          s0 + kc2 * 32 + quad * 8];
    // scale (faithful bug: *sqrt(D)=8) + causal mask on diagonal tile
    float sv[4][4];
    bool diag = (kt == ktmax);
#pragma unroll
    for (int ct = 0; ct < 4; ++ct)
#pragma unroll
      for (int r = 0; r < 4; ++r) {
        float xsc = sa[ct][r] * 8.0f;
        if (diag) {
          int sg = s0 + ct * 16 + c;
          int qg = qr0 + quad * 4 + r;
          if (sg > qg) xsc = -INFINITY;
        }
        sv[ct][r] = xsc;
      }
    // online softmax, rows = quad*4+r, reduce across the 16 lanes of the quad
    float alpha[4];
#pragma unroll
    for (int r = 0; r < 4; ++r) {
      float mx = fmaxf(fmaxf(sv[0][r], sv[1][r]), fmaxf(sv[2][r], sv[3][r]));
#pragma unroll
      for (int off = 1; off < 16; off <<= 1) mx = fmaxf(mx, __shfl_xor(mx, off, 64));
      float mnew = fmaxf(m_r[r], mx);
      alpha[r] = exp2f((m_r[r] - mnew) * LOG2E);
      m_r[r] = mnew;
      float rs = 0.0f;
#pragma unroll
      for (int ct = 0; ct < 4; ++ct) {
        float p = exp2f((sv[ct][r] - mnew) * LOG2E);
        sv[ct][r] = p;
        rs += p;
      }
#pragma unroll
      for (int off = 1; off < 16; off <<= 1) rs += __shfl_xor(rs, off, 64);
      l_r[r] = l_r[r] * alpha[r] + rs;
    }
#pragma unroll
    for (int dt = 0; dt < 4; ++dt)
#pragma unroll
      for (int r = 0; r < 4; ++r) o[dt][r] *= alpha[r];
    // P: C-layout -> per-wave LDS -> A-layout (single wave region, no barrier)
#pragma unroll
    for (int ct = 0; ct < 4; ++ct)
#pragma unroll
      for (int r = 0; r < 4; ++r)
        pS[wv][quad * 4 + r][ct * 16 + c] = (short)f2bf_u(sv[ct][r]);
    s16x8 pa[2];
#pragma unroll
    for (int kc2 = 0; kc2 < 2; ++kc2)
      pa[kc2] = *(const s16x8*)&pS[wv][c][kc2 * 32 + quad * 8];
    // O += P V
#pragma unroll
    for (int dt = 0; dt < 4; ++dt)
#pragma unroll
      for (int kc2 = 0; kc2 < 2; ++kc2)
        o[dt] = MFMA16(pa[kc2], vb[dt][kc2], o[dt], 0, 0, 0);
  }
  // write per-wave partials to LDS
#pragma unroll
  for (int dt = 0; dt < 4; ++dt)
#pragma unroll
    for (int r = 0; r < 4; ++r)
      oS[wv][quad * 4 + r][dt * 16 + c] = o[dt][r];
  if (c == 0) {
#pragma unroll
    for (int r = 0; r < 4; ++r) {
      mS[wv][quad * 4 + r] = m_r[r];
      lS[wv][quad * 4 + r] = l_r[r];
    }
  }
  __syncthreads();
  // merge 4 partials: thread t owns (row = t>>4, cols (t&15)*4 .. +3)
  {
    int r = t >> 4;
    int c4 = (t & 15) * 4;
    float m0 = mS[0][r], m1 = mS[1][r], m2 = mS[2][r], m3 = mS[3][r];
    float mstar = fmaxf(fmaxf(m0, m1), fmaxf(m2, m3));
    float s0 = exp2f((m0 - mstar) * LOG2E);
    float s1 = exp2f((m1 - mstar) * LOG2E);
    float s2 = exp2f((m2 - mstar) * LOG2E);
    float s3 = exp2f((m3 - mstar) * LOG2E);
    float lstar = s0 * lS[0][r] + s1 * lS[1][r] + s2 * lS[2][r] + s3 * lS[3][r];
    float inv = 1.0f / lstar;
    f32x4 oa;
#pragma unroll
    for (int j = 0; j < 4; ++j)
      oa[j] = (s0 * oS[0][r][c4 + j] + s1 * oS[1][r][c4 + j] +
               s2 * oS[2][r][c4 + j] + s3 * oS[3][r][c4 + j]) * inv;
    *(f32x4*)&outp[((size_t)n * LQ + qr0 + r) * 64 + c4] = oa;
  }
}

// ---------------------------------------------------------------------------
extern "C" void kernel_launch(void* const* d_in, const int* in_sizes, int n_in,
                              void* d_out, int out_size, void* d_ws, size_t ws_size,
                              hipStream_t stream) {
  const float* q = (const float*)d_in[0];
  const float* k = (const float*)d_in[1];
  const float* v = (const float*)d_in[2];
  const float* Wq = (const float*)d_in[3];
  const float* Wk = (const float*)d_in[4];
  const float* Wv = (const float*)d_in[5];
  // d_in[6] = attn_mask: ignored (known causal triu mask)
  float* out = (float*)d_out;

  char* ws = (char*)d_ws;
  // ws layout:
  //   wt   3*2*64*1024 shorts = 786432 B
  //   qhi/qlo/khi/klo  each 16384*64 shorts = 2097152 B
  //   vhT  8*64*2048 shorts = 2097152 B
  short* wt  = (short*)ws;
  short* qhi = (short*)(ws + 786432);
  short* qlo = qhi + (size_t)16384 * 64;
  short* khi = qlo + (size_t)16384 * 64;
  short* klo = khi + (size_t)16384 * 64;
  short* vhT = klo + (size_t)16384 * 64;

  wsplit_kernel<<<dim3(16, 3), 256, 0, stream>>>(Wq, Wk, Wv, wt);
  proj_kernel<<<dim3(256, 3), 256, 0, stream>>>(q, k, v, wt, qhi, qlo, khi, klo, vhT);
  attn_kernel<<<dim3(1024), 256, 0, stream>>>(qhi, qlo, khi, klo, vhT, out);
}

// Round 5
// 270.714 us; speedup vs baseline: 1.2608x; 1.1461x over previous
//
#include <hip/hip_runtime.h>
#include <math.h>

#define NB 8
#define LQ 2048
#define LOG2E 1.44269504088896f

typedef __attribute__((ext_vector_type(4))) float f32x4;
typedef __attribute__((ext_vector_type(8))) short s16x8;
typedef __attribute__((ext_vector_type(4))) int i32x4;

__device__ __forceinline__ unsigned f2bf_u(float f) {
  unsigned u = __builtin_bit_cast(unsigned, f);
  u += 0x7FFFu + ((u >> 16) & 1u); // RNE
  return u >> 16;
}
__device__ __forceinline__ float bf2f(unsigned h) {
  unsigned u = h << 16;
  return __builtin_bit_cast(float, u);
}

#define MFMA16 __builtin_amdgcn_mfma_f32_16x16x32_bf16

// ---------------------------------------------------------------------------
// Kernel 1: W [1024][64] fp32 -> wt in MFMA-FRAGMENT ORDER:
// per (z, kb): 16 KB tile = hi 8 frags [(cs*2+kc)*1KB] then lo 8 frags at
// +8 KB; within a frag, lane (quad*16+c) holds 8 shorts =
// W^T[d=cs*16+c][k=kb*64+kc*32+quad*8 .. +7]. Makes proj's B staging a pure
// linear copy and B-frag ds_reads lane-contiguous (conflict-free).
// ---------------------------------------------------------------------------
__global__ __launch_bounds__(256) void wsplit_kernel(
    const float* __restrict__ Wq, const float* __restrict__ Wk,
    const float* __restrict__ Wv, short* __restrict__ wt) {
  int bk = blockIdx.x; // 16 blocks of 64 k-rows (kb = bk)
  int z = blockIdx.y;  // tensor
  const float* W = (z == 0) ? Wq : (z == 1) ? Wk : Wv;
  __shared__ float tile[64][65];
  int t = threadIdx.x;
#pragma unroll
  for (int it = 0; it < 16; ++it) {
    int kk = it * 4 + (t >> 6);
    int d = t & 63;
    tile[kk][d] = W[(size_t)(bk * 64 + kk) * 64 + d];
  }
  __syncthreads();
#pragma unroll
  for (int it = 0; it < 16; ++it) {
    int d = it * 4 + (t >> 6);
    int kk = t & 63;
    float f = tile[kk][d];
    unsigned h = f2bf_u(f);
    unsigned l = f2bf_u(f - bf2f(h));
    int cs = d >> 4, cc = d & 15;
    int kc = kk >> 5, qd = (kk >> 3) & 3, j = kk & 7;
    size_t base = (size_t)z * 131072 + (size_t)bk * 8192 +
                  (size_t)(cs * 2 + kc) * 512 + (size_t)(qd * 16 + cc) * 8 + j;
    wt[base] = (short)h;
    wt[base + 4096] = (short)l;
  }
}

// ---------------------------------------------------------------------------
// Kernel 2: projection GEMM y = x @ W via split-bf16 MFMA.
// A: fp32 64x64 tile via global_load_lds, double-buffered, source-swizzled
//    (r3-verified path, unchanged).
// B: fragment-ordered 16 KB tile; B(kb+1) loaded global->regs during step kb
//    (linear, 4x16B/thread) and written to LDS with ds_write_b128 after bar1
//    (B(kb) reads complete then). Single 16 KB B buffer, time-multiplexed.
// Per wave-step: 4 gload_lds + 4 global reg loads + 4 ds_write + 20 ds_read,
// 24 MFMA, 2 barriers. LDS 48 KB -> 3 blocks/CU; grid (256,3) = 3 blocks/CU.
// ---------------------------------------------------------------------------
__global__ __launch_bounds__(256, 3) void proj_kernel(
    const float* __restrict__ xq, const float* __restrict__ xk,
    const float* __restrict__ xv, const short* __restrict__ wt,
    short* __restrict__ qhi, short* __restrict__ qlo,
    short* __restrict__ khi, short* __restrict__ klo,
    short* __restrict__ vhT) {
  int z = blockIdx.y;
  const float* x = (z == 0) ? xq : (z == 1) ? xk : xv;
  const char* wb = (const char*)(wt + (size_t)z * 131072); // frag-ordered
  int row0 = blockIdx.x * 64;
  int t = threadIdx.x;
  int wv = t >> 6, lane = t & 63;
  int c = lane & 15, quad = lane >> 4;

  __shared__ __align__(16) float xa[2][4096]; // 32 KB: A dbuf
  __shared__ __align__(16) short bs[8192];    // 16 KB: B buffer
  char* bsb = (char*)bs;

  const float* xg = x + (size_t)row0 * 1024;

  // A staging (r3-verified): linear LDS dest, source-swizzled 16B chunks.
#define STAGE_A(buf, kb)                                                      \
  {                                                                           \
    _Pragma("unroll") for (int j = 0; j < 4; ++j) {                           \
      int row = wv * 16 + j * 4 + quad;                                       \
      const float* src = xg + (size_t)row * 1024 + (kb) * 64 +                \
                         ((c ^ (row & 7)) << 2);                              \
      float* dst = &xa[buf][(wv * 4 + j) * 256];                              \
      __builtin_amdgcn_global_load_lds(                                       \
          (const __attribute__((address_space(1))) unsigned*)src,             \
          (__attribute__((address_space(3))) unsigned*)dst, 16, 0, 0);        \
    }                                                                         \
  }

  f32x4 acc[4] = {};
  i32x4 breg[4];
  // prologue: stage A(0) async; copy B(0) via regs -> LDS
  STAGE_A(0, 0);
#pragma unroll
  for (int i = 0; i < 4; ++i)
    breg[i] = *(const i32x4*)(wb + i * 4096 + t * 16);
#pragma unroll
  for (int i = 0; i < 4; ++i)
    *(i32x4*)(bsb + i * 4096 + t * 16) = breg[i];
  __syncthreads(); // drains gload_lds vmcnt + ds_writes -> A(0), B(0) ready

  int cur = 0;
  int rowl = wv * 16 + c;
  for (int kb = 0; kb < 16; ++kb) {
    if (kb < 15) {
      STAGE_A(cur ^ 1, kb + 1); // abuf[cur^1] dead since bar1 of kb-1
#pragma unroll
      for (int i = 0; i < 4; ++i)
        breg[i] = *(const i32x4*)(wb + (size_t)(kb + 1) * 16384 + i * 4096 + t * 16);
    }
    // B(kb) fragments: lane-contiguous ds_read_b128, conflict-free
    s16x8 bh[4][2], bl[4][2];
#pragma unroll
    for (int cs = 0; cs < 4; ++cs)
#pragma unroll
      for (int kc = 0; kc < 2; ++kc) {
        bh[cs][kc] = *(const s16x8*)(bsb + (cs * 2 + kc) * 1024 + lane * 16);
        bl[cs][kc] = *(const s16x8*)(bsb + 8192 + (cs * 2 + kc) * 1024 + lane * 16);
      }
    // A(kb) fragments (swizzled read) + split-bf16 convert
    const float* arow = &xa[cur][rowl * 64];
    s16x8 ah[2], al[2];
#pragma unroll
    for (int kc = 0; kc < 2; ++kc) {
      int ch0 = ((kc * 8 + quad * 2 + 0) ^ (c & 7)) << 2;
      int ch1 = ((kc * 8 + quad * 2 + 1) ^ (c & 7)) << 2;
      f32x4 a0 = *(const f32x4*)(arow + ch0);
      f32x4 a1 = *(const f32x4*)(arow + ch1);
#pragma unroll
      for (int j = 0; j < 4; ++j) {
        unsigned h;
        h = f2bf_u(a0[j]); ah[kc][j] = (short)h;
        al[kc][j] = (short)f2bf_u(a0[j] - bf2f(h));
        h = f2bf_u(a1[j]); ah[kc][4 + j] = (short)h;
        al[kc][4 + j] = (short)f2bf_u(a1[j] - bf2f(h));
      }
    }
    __syncthreads(); // bar1: all waves done reading B(kb) frags and A(cur)
    if (kb < 15) {
      // overwrite B buffer with B(kb+1); visible after bar2
#pragma unroll
      for (int i = 0; i < 4; ++i)
        *(i32x4*)(bsb + i * 4096 + t * 16) = breg[i];
    }
    // MFMA: split-bf16 (hh + hl + lh), same operand order as verified rounds
#pragma unroll
    for (int kc = 0; kc < 2; ++kc)
#pragma unroll
      for (int cs = 0; cs < 4; ++cs) {
        acc[cs] = MFMA16(ah[kc], bh[cs][kc], acc[cs], 0, 0, 0);
        acc[cs] = MFMA16(ah[kc], bl[cs][kc], acc[cs], 0, 0, 0);
        acc[cs] = MFMA16(al[kc], bh[cs][kc], acc[cs], 0, 0, 0);
      }
    __syncthreads(); // bar2: drains A-stage vmcnt + B ds_writes for next iter
    cur ^= 1;
  }
#undef STAGE_A
  // epilogue: C layout row=(quad*4+r), col=(lane&15)
  if (z < 2) {
    short* hi = (z == 0) ? qhi : khi;
    short* lo = (z == 0) ? qlo : klo;
#pragma unroll
    for (int cs = 0; cs < 4; ++cs)
#pragma unroll
      for (int r = 0; r < 4; ++r) {
        int row = row0 + wv * 16 + quad * 4 + r;
        int col = cs * 16 + c;
        float val = acc[cs][r];
        unsigned h = f2bf_u(val);
        unsigned l = f2bf_u(val - bf2f(h));
        hi[(size_t)row * 64 + col] = (short)h;
        lo[(size_t)row * 64 + col] = (short)l;
      }
  } else {
    // V: transpose 64x64 block -> vhT [n][64][2048]; vtile reuses bs
    // (dead after final barrier; 9216 B <= 16384 B).
    short(*vtile)[72] = (short(*)[72])bs;
#pragma unroll
    for (int cs = 0; cs < 4; ++cs)
#pragma unroll
      for (int r = 0; r < 4; ++r)
        vtile[cs * 16 + c][wv * 16 + quad * 4 + r] = (short)f2bf_u(acc[cs][r]);
    __syncthreads();
    int n = row0 >> 11;
    int sbase = row0 & 2047;
    int d = t >> 2, sc = (t & 3) * 16;
#pragma unroll
    for (int j = 0; j < 2; ++j) {
      s16x8 vv = *(const s16x8*)&vtile[d][sc + j * 8];
      *(s16x8*)&vhT[((size_t)n * 64 + d) * LQ + sbase + sc + j * 8] = vv;
    }
  }
}

// ---------------------------------------------------------------------------
// Kernel 3: causal flash attention, 4-way k-split. UNCHANGED (frozen so the
// total delta isolates the proj change).
// ---------------------------------------------------------------------------
__global__ __launch_bounds__(256, 3) void attn_kernel(
    const short* __restrict__ qhi, const short* __restrict__ qlo,
    const short* __restrict__ khi, const short* __restrict__ klo,
    const short* __restrict__ vhT, float* __restrict__ outp) {
  int bid = blockIdx.x;
  int n = bid & 7;
  int qt = 127 - (bid >> 3); // heavy (high-qt) tiles first
  int t = threadIdx.x;
  int wv = t >> 6, lane = t & 63;
  int c = lane & 15, quad = lane >> 4;
  int qr0 = qt * 16;
  __shared__ short pS[4][16][72]; // per-wave P transpose buffer
  __shared__ float mS[4][16], lS[4][16];
  __shared__ float oS[4][16][64];
  // Q A-fragments: A[m=lane&15][k=quad*8+j], hi/lo
  s16x8 qfh[2], qfl[2];
  size_t qbase = ((size_t)n * LQ + qr0 + c) * 64;
#pragma unroll
  for (int kc = 0; kc < 2; ++kc) {
    qfh[kc] = *(const s16x8*)&qhi[qbase + kc * 32 + quad * 8];
    qfl[kc] = *(const s16x8*)&qlo[qbase + kc * 32 + quad * 8];
  }
  f32x4 o[4] = {};
  float m_r[4], l_r[4];
#pragma unroll
  for (int r = 0; r < 4; ++r) { m_r[r] = -INFINITY; l_r[r] = 0.0f; }
  int ktmax = qt >> 2; // last (diagonal) 64-wide k-tile
  for (int kt = wv; kt <= ktmax; kt += 4) {
    int s0 = kt * 64;
    size_t kbase = ((size_t)n * LQ + s0) * 64;
    // S = Q K^T (split-bf16: hh + hl + lh); B-frags direct from global
    f32x4 sa[4] = {};
#pragma unroll
    for (int ct = 0; ct < 4; ++ct) {
      size_t rb = kbase + (size_t)(ct * 16 + c) * 64;
#pragma unroll
      for (int kc = 0; kc < 2; ++kc) {
        s16x8 bh = *(const s16x8*)&khi[rb + kc * 32 + quad * 8];
        s16x8 bl = *(const s16x8*)&klo[rb + kc * 32 + quad * 8];
        sa[ct] = MFMA16(qfh[kc], bh, sa[ct], 0, 0, 0);
        sa[ct] = MFMA16(qfh[kc], bl, sa[ct], 0, 0, 0);
        sa[ct] = MFMA16(qfl[kc], bh, sa[ct], 0, 0, 0);
      }
    }
    // prefetch V B-fragments (independent of softmax; hides L2 latency)
    s16x8 vb[4][2];
#pragma unroll
    for (int dt = 0; dt < 4; ++dt)
#pragma unroll
      for (int kc2 = 0; kc2 < 2; ++kc2)
        vb[dt][kc2] = *(const s16x8*)&vhT[((size_t)n * 64 + dt * 16 + c) * LQ +
                                          s0 + kc2 * 32 + quad * 8];
    // scale (faithful bug: *sqrt(D)=8) + causal mask on diagonal tile
    float sv[4][4];
    bool diag = (kt == ktmax);
#pragma unroll
    for (int ct = 0; ct < 4; ++ct)
#pragma unroll
      for (int r = 0; r < 4; ++r) {
        float xsc = sa[ct][r] * 8.0f;
        if (diag) {
          int sg = s0 + ct * 16 + c;
          int qg = qr0 + quad * 4 + r;
          if (sg > qg) xsc = -INFINITY;
        }
        sv[ct][r] = xsc;
      }
    // online softmax, rows = quad*4+r, reduce across the 16 lanes of the quad
    float alpha[4];
#pragma unroll
    for (int r = 0; r < 4; ++r) {
      float mx = fmaxf(fmaxf(sv[0][r], sv[1][r]), fmaxf(sv[2][r], sv[3][r]));
#pragma unroll
      for (int off = 1; off < 16; off <<= 1) mx = fmaxf(mx, __shfl_xor(mx, off, 64));
      float mnew = fmaxf(m_r[r], mx);
      alpha[r] = exp2f((m_r[r] - mnew) * LOG2E);
      m_r[r] = mnew;
      float rs = 0.0f;
#pragma unroll
      for (int ct = 0; ct < 4; ++ct) {
        float p = exp2f((sv[ct][r] - mnew) * LOG2E);
        sv[ct][r] = p;
        rs += p;
      }
#pragma unroll
      for (int off = 1; off < 16; off <<= 1) rs += __shfl_xor(rs, off, 64);
      l_r[r] = l_r[r] * alpha[r] + rs;
    }
#pragma unroll
    for (int dt = 0; dt < 4; ++dt)
#pragma unroll
      for (int r = 0; r < 4; ++r) o[dt][r] *= alpha[r];
    // P: C-layout -> per-wave LDS -> A-layout (single wave region, no barrier)
#pragma unroll
    for (int ct = 0; ct < 4; ++ct)
#pragma unroll
      for (int r = 0; r < 4; ++r)
        pS[wv][quad * 4 + r][ct * 16 + c] = (short)f2bf_u(sv[ct][r]);
    s16x8 pa[2];
#pragma unroll
    for (int kc2 = 0; kc2 < 2; ++kc2)
      pa[kc2] = *(const s16x8*)&pS[wv][c][kc2 * 32 + quad * 8];
    // O += P V
#pragma unroll
    for (int dt = 0; dt < 4; ++dt)
#pragma unroll
      for (int kc2 = 0; kc2 < 2; ++kc2)
        o[dt] = MFMA16(pa[kc2], vb[dt][kc2], o[dt], 0, 0, 0);
  }
  // write per-wave partials to LDS
#pragma unroll
  for (int dt = 0; dt < 4; ++dt)
#pragma unroll
    for (int r = 0; r < 4; ++r)
      oS[wv][quad * 4 + r][dt * 16 + c] = o[dt][r];
  if (c == 0) {
#pragma unroll
    for (int r = 0; r < 4; ++r) {
      mS[wv][quad * 4 + r] = m_r[r];
      lS[wv][quad * 4 + r] = l_r[r];
    }
  }
  __syncthreads();
  // merge 4 partials: thread t owns (row = t>>4, cols (t&15)*4 .. +3)
  {
    int r = t >> 4;
    int c4 = (t & 15) * 4;
    float m0 = mS[0][r], m1 = mS[1][r], m2 = mS[2][r], m3 = mS[3][r];
    float mstar = fmaxf(fmaxf(m0, m1), fmaxf(m2, m3));
    float s0 = exp2f((m0 - mstar) * LOG2E);
    float s1 = exp2f((m1 - mstar) * LOG2E);
    float s2 = exp2f((m2 - mstar) * LOG2E);
    float s3 = exp2f((m3 - mstar) * LOG2E);
    float lstar = s0 * lS[0][r] + s1 * lS[1][r] + s2 * lS[2][r] + s3 * lS[3][r];
    float inv = 1.0f / lstar;
    f32x4 oa;
#pragma unroll
    for (int j = 0; j < 4; ++j)
      oa[j] = (s0 * oS[0][r][c4 + j] + s1 * oS[1][r][c4 + j] +
               s2 * oS[2][r][c4 + j] + s3 * oS[3][r][c4 + j]) * inv;
    *(f32x4*)&outp[((size_t)n * LQ + qr0 + r) * 64 + c4] = oa;
  }
}

// ---------------------------------------------------------------------------
extern "C" void kernel_launch(void* const* d_in, const int* in_sizes, int n_in,
                              void* d_out, int out_size, void* d_ws, size_t ws_size,
                              hipStream_t stream) {
  const float* q = (const float*)d_in[0];
  const float* k = (const float*)d_in[1];
  const float* v = (const float*)d_in[2];
  const float* Wq = (const float*)d_in[3];
  const float* Wk = (const float*)d_in[4];
  const float* Wv = (const float*)d_in[5];
  // d_in[6] = attn_mask: ignored (known causal triu mask)
  float* out = (float*)d_out;

  char* ws = (char*)d_ws;
  // ws layout:
  //   wt   3*16*8192 shorts = 786432 B (fragment-ordered)
  //   qhi/qlo/khi/klo  each 16384*64 shorts = 2097152 B
  //   vhT  8*64*2048 shorts = 2097152 B
  short* wt  = (short*)ws;
  short* qhi = (short*)(ws + 786432);
  short* qlo = qhi + (size_t)16384 * 64;
  short* khi = qlo + (size_t)16384 * 64;
  short* klo = khi + (size_t)16384 * 64;
  short* vhT = klo + (size_t)16384 * 64;

  wsplit_kernel<<<dim3(16, 3), 256, 0, stream>>>(Wq, Wk, Wv, wt);
  proj_kernel<<<dim3(256, 3), 256, 0, stream>>>(q, k, v, wt, qhi, qlo, khi, klo, vhT);
  attn_kernel<<<dim3(1024), 256, 0, stream>>>(qhi, qlo, khi, klo, vhT, out);
}